// Round 1
// 339.580 us; speedup vs baseline: 1.0202x; 1.0202x over previous
//
#include <hip/hip_runtime.h>

// Haar 3D wavelet transform, x:(2,3,33,512,512) f32 -> out:(2,24,17,256,256) f32.
// channel = f*3 + c, f bit layout: f = ft*4 + fh*2 + fw, sign = (-1)^(ft*t+fh*h+fw*w).
// Memory-bound pure stream: ~208 MB read + ~214 MB write, zero reuse.
// This rev: non-temporal loads/stores (nt flag) to bypass L1/L2/L3 allocation —
// streaming data with no reuse should not thrash the cache hierarchy.

#define HAAR_SCALE 0.3536f

typedef float f4 __attribute__((ext_vector_type(4)));

__global__ __launch_bounds__(256) void haar3d_kernel(const float* __restrict__ x,
                                                     float* __restrict__ out) {
    // block = 256 threads: 64 tw-groups (4 out cols each) x 4 rows
    const int tw   = threadIdx.x & 63;           // output cols 4*tw .. 4*tw+3
    const int hsub = threadIdx.x >> 6;           // 0..3
    const int h    = (blockIdx.x << 2) + hsub;   // 0..255 output row
    const int t    = blockIdx.y;                 // 0..16 output frame
    const int bc   = blockIdx.z;                 // 0..5 (b*3 + c)
    const int b    = bc / 3;
    const int c    = bc - b * 3;

    // causal replicate pad: padded frames (2t, 2t+1) = orig frames (max(2t-1,0), 2t)
    const int fr0 = max(2 * t - 1, 0);
    const int fr1 = 2 * t;

    const long long in_plane = (long long)bc * 33LL * 512LL * 512LL;
    const float* r00 = x + in_plane + ((long long)fr0 * 512 + 2 * h) * 512 + 8 * tw;
    const float* r01 = r00 + 512;                         // fr0, row 2h+1
    const float* r10 = x + in_plane + ((long long)fr1 * 512 + 2 * h) * 512 + 8 * tw;
    const float* r11 = r10 + 512;                         // fr1, row 2h+1

    // 8 cols per (frame,row): two nt float4 loads each (32B/lane, back-to-back
    // instructions cover each cache line fully)
    f4 a00 = __builtin_nontemporal_load((const f4*)r00);
    f4 b00 = __builtin_nontemporal_load((const f4*)r00 + 1);
    f4 a01 = __builtin_nontemporal_load((const f4*)r01);
    f4 b01 = __builtin_nontemporal_load((const f4*)r01 + 1);
    f4 a10 = __builtin_nontemporal_load((const f4*)r10);
    f4 b10 = __builtin_nontemporal_load((const f4*)r10 + 1);
    f4 a11 = __builtin_nontemporal_load((const f4*)r11);
    f4 b11 = __builtin_nontemporal_load((const f4*)r11 + 1);

    float in00[8] = {a00.x, a00.y, a00.z, a00.w, b00.x, b00.y, b00.z, b00.w};
    float in01[8] = {a01.x, a01.y, a01.z, a01.w, b01.x, b01.y, b01.z, b01.w};
    float in10[8] = {a10.x, a10.y, a10.z, a10.w, b10.x, b10.y, b10.z, b10.w};
    float in11[8] = {a11.x, a11.y, a11.z, a11.w, b11.x, b11.y, b11.z, b11.w};

    float res[8][4];
#pragma unroll
    for (int j = 0; j < 4; ++j) {
        const float v000 = in00[2 * j], v001 = in00[2 * j + 1];  // t0,h0,w0/w1
        const float v010 = in01[2 * j], v011 = in01[2 * j + 1];  // t0,h1
        const float v100 = in10[2 * j], v101 = in10[2 * j + 1];  // t1,h0
        const float v110 = in11[2 * j], v111 = in11[2 * j + 1];  // t1,h1
        // stage 1: w butterfly
        const float pw00 = v000 + v001, mw00 = v000 - v001;
        const float pw01 = v010 + v011, mw01 = v010 - v011;
        const float pw10 = v100 + v101, mw10 = v100 - v101;
        const float pw11 = v110 + v111, mw11 = v110 - v111;
        // stage 2: h butterfly
        const float pp0 = pw00 + pw01, pm0 = pw00 - pw01;
        const float mp0 = mw00 + mw01, mm0 = mw00 - mw01;
        const float pp1 = pw10 + pw11, pm1 = pw10 - pw11;
        const float mp1 = mw10 + mw11, mm1 = mw10 - mw11;
        // stage 3: t butterfly; f = ft*4 + fh*2 + fw
        res[0][j] = (pp0 + pp1) * HAAR_SCALE;  // 000
        res[1][j] = (mp0 + mp1) * HAAR_SCALE;  // 001 w-flip
        res[2][j] = (pm0 + pm1) * HAAR_SCALE;  // 010 h-flip
        res[3][j] = (mm0 + mm1) * HAAR_SCALE;  // 011
        res[4][j] = (pp0 - pp1) * HAAR_SCALE;  // 100 t-flip
        res[5][j] = (mp0 - mp1) * HAAR_SCALE;  // 101
        res[6][j] = (pm0 - pm1) * HAAR_SCALE;  // 110
        res[7][j] = (mm0 - mm1) * HAAR_SCALE;  // 111
    }

    // out index: ((b*24 + f*3 + c)*17 + t)*256*256 + h*256 + 4*tw
    const long long fstride = 3LL * 17LL * 256LL * 256LL;
    const long long obase =
        (((long long)(b * 24 + c) * 17 + t) * 256LL + h) * 256LL + 4LL * tw;
#pragma unroll
    for (int f = 0; f < 8; ++f) {
        f4 v = {res[f][0], res[f][1], res[f][2], res[f][3]};
        __builtin_nontemporal_store(v, (f4*)(out + obase + (long long)f * fstride));
    }
}

extern "C" void kernel_launch(void* const* d_in, const int* in_sizes, int n_in,
                              void* d_out, int out_size, void* d_ws, size_t ws_size,
                              hipStream_t stream) {
    const float* x = (const float*)d_in[0];
    float* out = (float*)d_out;
    dim3 grid(64, 17, 6);   // 64 row-groups (4 rows each), 17 frames, 6 (b,c) planes
    dim3 block(256);
    haar3d_kernel<<<grid, block, 0, stream>>>(x, out);
}

// Round 2
// 337.703 us; speedup vs baseline: 1.0258x; 1.0056x over previous
//
#include <hip/hip_runtime.h>

// Haar 3D wavelet transform, x:(2,3,33,512,512) f32 -> out:(2,24,17,256,256) f32.
// channel = f*3 + c, f bit layout: f = ft*4 + fh*2 + fw, sign = (-1)^(ft*t+fh*h+fw*w).
// Memory-bound pure stream: ~208 MB read + ~214 MB write, zero reuse.
// This rev: DENSE per-instruction VMEM. Each wave owns one output row; lane l
// loads float4 at 16*l within a 1KB half-row (every 128B line requested exactly
// once by exactly one instruction), computes out cols {2l, 2l+1} per half, and
// stores float2 per filter (512B dense per wave store). Previous layout had
// stride-32B 50%-dense loads -> every line requested by two instructions, which
// under nt (evict-first) risks duplicate HBM fetches.

#define HAAR_SCALE 0.3536f

typedef float f4 __attribute__((ext_vector_type(4)));
typedef float f2 __attribute__((ext_vector_type(2)));

__global__ __launch_bounds__(256) void haar3d_kernel(const float* __restrict__ x,
                                                     float* __restrict__ out) {
    const int lane = threadIdx.x & 63;           // 0..63
    const int wv   = threadIdx.x >> 6;           // wave 0..3
    const int h    = (blockIdx.x << 2) + wv;     // output row 0..255 (one per wave)
    const int t    = blockIdx.y;                 // 0..16 output frame
    const int bc   = blockIdx.z;                 // 0..5 (b*3 + c)
    const int b    = bc / 3;
    const int c    = bc - b * 3;

    // causal replicate pad: padded frames (2t, 2t+1) = orig frames (max(2t-1,0), 2t)
    const int fr0 = max(2 * t - 1, 0);
    const int fr1 = 2 * t;

    const long long in_plane = (long long)bc * 33LL * 512LL * 512LL;
    const float* r00 = x + in_plane + ((long long)fr0 * 512 + 2 * h) * 512;  // t0, row 2h
    const float* r01 = r00 + 512;                                            // t0, row 2h+1
    const float* r10 = x + in_plane + ((long long)fr1 * 512 + 2 * h) * 512;  // t1, row 2h
    const float* r11 = r10 + 512;                                            // t1, row 2h+1

    // 8 dense float4 loads: half q covers input cols [256q, 256q+256);
    // lane l gets input cols 256q + 4l .. +3 of all 4 rows.
    f4 v00[2], v01[2], v10[2], v11[2];
#pragma unroll
    for (int q = 0; q < 2; ++q) {
        const int off = 256 * q + 4 * lane;
        v00[q] = __builtin_nontemporal_load((const f4*)(r00 + off));
        v01[q] = __builtin_nontemporal_load((const f4*)(r01 + off));
        v10[q] = __builtin_nontemporal_load((const f4*)(r10 + off));
        v11[q] = __builtin_nontemporal_load((const f4*)(r11 + off));
    }

    // out index: ((b*24 + f*3 + c)*17 + t)*256*256 + h*256 + ocol
    const long long fstride = 3LL * 17LL * 256LL * 256LL;
    const long long obase =
        (((long long)(b * 24 + c) * 17 + t) * 256LL + h) * 256LL;

#pragma unroll
    for (int q = 0; q < 2; ++q) {
        f2 res[8];
#pragma unroll
        for (int j = 0; j < 2; ++j) {
            const float v000 = v00[q][2 * j], v001 = v00[q][2 * j + 1];  // t0,h0,w0/w1
            const float v010 = v01[q][2 * j], v011 = v01[q][2 * j + 1];  // t0,h1
            const float v100 = v10[q][2 * j], v101 = v10[q][2 * j + 1];  // t1,h0
            const float v110 = v11[q][2 * j], v111 = v11[q][2 * j + 1];  // t1,h1
            // stage 1: w butterfly
            const float pw00 = v000 + v001, mw00 = v000 - v001;
            const float pw01 = v010 + v011, mw01 = v010 - v011;
            const float pw10 = v100 + v101, mw10 = v100 - v101;
            const float pw11 = v110 + v111, mw11 = v110 - v111;
            // stage 2: h butterfly
            const float pp0 = pw00 + pw01, pm0 = pw00 - pw01;
            const float mp0 = mw00 + mw01, mm0 = mw00 - mw01;
            const float pp1 = pw10 + pw11, pm1 = pw10 - pw11;
            const float mp1 = mw10 + mw11, mm1 = mw10 - mw11;
            // stage 3: t butterfly; f = ft*4 + fh*2 + fw
            res[0][j] = (pp0 + pp1) * HAAR_SCALE;  // 000
            res[1][j] = (mp0 + mp1) * HAAR_SCALE;  // 001 w-flip
            res[2][j] = (pm0 + pm1) * HAAR_SCALE;  // 010 h-flip
            res[3][j] = (mm0 + mm1) * HAAR_SCALE;  // 011
            res[4][j] = (pp0 - pp1) * HAAR_SCALE;  // 100 t-flip
            res[5][j] = (mp0 - mp1) * HAAR_SCALE;  // 101
            res[6][j] = (pm0 - pm1) * HAAR_SCALE;  // 110
            res[7][j] = (mm0 - mm1) * HAAR_SCALE;  // 111
        }
        // lane l writes out cols 128q + 2l, 2l+1 -> 512B dense per wave store
        const long long ocol = 128LL * q + 2 * lane;
#pragma unroll
        for (int f = 0; f < 8; ++f) {
            __builtin_nontemporal_store(
                res[f], (f2*)(out + obase + (long long)f * fstride + ocol));
        }
    }
}

extern "C" void kernel_launch(void* const* d_in, const int* in_sizes, int n_in,
                              void* d_out, int out_size, void* d_ws, size_t ws_size,
                              hipStream_t stream) {
    const float* x = (const float*)d_in[0];
    float* out = (float*)d_out;
    dim3 grid(64, 17, 6);   // 64 row-groups (4 rows each), 17 frames, 6 (b,c) planes
    dim3 block(256);
    haar3d_kernel<<<grid, block, 0, stream>>>(x, out);
}